// Round 1
// baseline (146.076 us; speedup 1.0000x reference)
//
#include <hip/hip_runtime.h>
#include <hip/hip_bf16.h>
#include <stdint.h>

#define N_NODES 4096
#define INF_ 512
#define OUTF_ 512

typedef unsigned short u16;
typedef __attribute__((ext_vector_type(8))) short bf16x8;
typedef __attribute__((ext_vector_type(4))) float f32x4;

__device__ __forceinline__ u16 f2bf(float f) {
    union { float f; uint32_t u; } v; v.f = f;
    uint32_t u = v.u;
    uint32_t r = u + 0x7FFFu + ((u >> 16) & 1u);   // round-to-nearest-even
    return (u16)(r >> 16);
}

__device__ __forceinline__ void async16(const void* gsrc, void* ldst) {
    __builtin_amdgcn_global_load_lds(
        (const __attribute__((address_space(1))) unsigned int*)gsrc,
        (__attribute__((address_space(3))) unsigned int*)ldst,
        16, 0, 0);
}

// ---- convert X -> bf16 (row-major) and W -> bf16 transposed [OUTF][INF] ----
__global__ void convert_kernel(const float* __restrict__ X, const float* __restrict__ W,
                               u16* __restrict__ Xbf, u16* __restrict__ WT) {
    int tid = blockIdx.x * blockDim.x + threadIdx.x;
    if (tid < N_NODES * INF_) Xbf[tid] = f2bf(X[tid]);
    if (tid < INF_ * OUTF_) {
        int n = tid >> 9;          // out-feature
        int k = tid & 511;         // in-feature
        WT[tid] = f2bf(W[k * OUTF_ + n]);   // WT[n][k] = W[k][n]
    }
}

// ---- edge weights: Abf[i] = bf16(dot(E[i,0:4], wq)) ----
__global__ void edge_kernel(const float4* __restrict__ E4, const float* __restrict__ wq,
                            u16* __restrict__ Abf) {
    const float w0 = wq[0], w1 = wq[1], w2 = wq[2], w3 = wq[3];
    const int lane = threadIdx.x & 63;
    const long wave = (long)((blockIdx.x * blockDim.x + threadIdx.x) >> 6);
    const long base = wave * 512;
#pragma unroll
    for (int j = 0; j < 8; ++j) {
        long idx = base + j * 64 + lane;
        float4 e = E4[idx];
        float a = e.x * w0 + e.y * w1 + e.z * w2 + e.w * w3;
        Abf[idx] = f2bf(a);
    }
}

// ---- bf16 MFMA GEMM, 128x128 tile, BK=32, 4 waves (2x2), m97 structure ----
// A: [M][K] row-major bf16, stride K. B: [N][K] row-major bf16 (i.e. B^T layout).
// TRANS=false: outF[row*OUTF_+col] = acc + bias[col]
// TRANS=true : outT[col*N_NODES+row] = bf16(acc)
template<int K, bool TRANS>
__global__ __launch_bounds__(256)
void gemm_bf16(const u16* __restrict__ A, const u16* __restrict__ B,
               float* __restrict__ outF, u16* __restrict__ outT,
               const float* __restrict__ bias) {
    __shared__ u16 As[128][32];
    __shared__ u16 Bs[128][32];

    const int tid  = threadIdx.x;
    const int lane = tid & 63;
    const int w    = tid >> 6;        // wave 0..3
    const int wr   = w >> 1;          // wave row 0..1
    const int wc   = w & 1;           // wave col 0..1
    const int brow = blockIdx.x * 128;
    const int bcol = blockIdx.y * 128;

    f32x4 acc[4][4] = {};

    const int sr = w * 32 + (lane >> 2);   // staging row (this lane, first of two instrs)
    const int sc = (lane & 3) * 8;         // k element offset within tile

    for (int kt = 0; kt < K; kt += 32) {
        __syncthreads();
        // stage A tile (128 x 32) and B tile (128 x 32): each wave issues 2+2 loads
        async16(&A[(long)(brow + sr) * K + kt + sc],      &As[w * 32][0]);
        async16(&A[(long)(brow + sr + 16) * K + kt + sc], &As[w * 32 + 16][0]);
        async16(&B[(long)(bcol + sr) * K + kt + sc],      &Bs[w * 32][0]);
        async16(&B[(long)(bcol + sr + 16) * K + kt + sc], &Bs[w * 32 + 16][0]);
        __syncthreads();   // compiler drains vmcnt(0) before barrier

        bf16x8 af[4], bfr[4];
#pragma unroll
        for (int m = 0; m < 4; ++m)
            af[m] = *(const bf16x8*)&As[wr * 64 + m * 16 + (lane & 15)][(lane >> 4) * 8];
#pragma unroll
        for (int n = 0; n < 4; ++n)
            bfr[n] = *(const bf16x8*)&Bs[wc * 64 + n * 16 + (lane & 15)][(lane >> 4) * 8];
#pragma unroll
        for (int m = 0; m < 4; ++m)
#pragma unroll
            for (int n = 0; n < 4; ++n)
                acc[m][n] = __builtin_amdgcn_mfma_f32_16x16x32_bf16(af[m], bfr[n], acc[m][n], 0, 0, 0);
    }

    // epilogue: C/D layout col=lane&15, row=(lane>>4)*4+reg  [verified m89/m91]
#pragma unroll
    for (int m = 0; m < 4; ++m) {
#pragma unroll
        for (int n = 0; n < 4; ++n) {
            int col  = bcol + wc * 64 + n * 16 + (lane & 15);
            int row0 = brow + wr * 64 + m * 16 + (lane >> 4) * 4;
            if (TRANS) {
#pragma unroll
                for (int r = 0; r < 4; ++r)
                    outT[(long)col * N_NODES + row0 + r] = f2bf(acc[m][n][r]);
            } else {
                float bv = bias[col];
#pragma unroll
                for (int r = 0; r < 4; ++r)
                    outF[(long)(row0 + r) * OUTF_ + col] = acc[m][n][r] + bv;
            }
        }
    }
}

extern "C" void kernel_launch(void* const* d_in, const int* in_sizes, int n_in,
                              void* d_out, int out_size, void* d_ws, size_t ws_size,
                              hipStream_t stream) {
    const float* X    = (const float*)d_in[0];
    // d_in[1] = adj, unused by forward
    const float* E    = (const float*)d_in[2];
    const float* W    = (const float*)d_in[3];
    const float* wq   = (const float*)d_in[4];
    const float* bias = (const float*)d_in[5];
    float* out = (float*)d_out;

    char* ws = (char*)d_ws;
    // layout: ST [0,4MB) ; Abf [4MB,36MB) ; Xbf/WT overlap inside Abf region
    u16* ST  = (u16*)ws;                         // 512 x 4096 bf16 (support transposed)
    u16* Abf = (u16*)(ws + (4l << 20));          // 4096 x 4096 bf16
    u16* Xbf = (u16*)(ws + (4l << 20));          // 4096 x 512 bf16 (consumed before edge)
    u16* WT  = (u16*)(ws + (8l << 20));          // 512 x 512 bf16  (consumed before edge)

    // 1) converts (Xbf, WT)
    convert_kernel<<<8192, 256, 0, stream>>>(X, W, Xbf, WT);
    // 2) support^T = (X @ W)^T in bf16
    gemm_bf16<512, true><<<dim3(32, 4), 256, 0, stream>>>(Xbf, WT, nullptr, ST, nullptr);
    // 3) edge weights -> Abf (overwrites Xbf/WT region, already consumed)
    edge_kernel<<<8192, 256, 0, stream>>>((const float4*)E, wq, Abf);
    // 4) out = Abf @ support + bias
    gemm_bf16<4096, false><<<dim3(32, 4), 256, 0, stream>>>(Abf, ST, out, nullptr, bias);
}

// Round 2
// 114.495 us; speedup vs baseline: 1.2758x; 1.2758x over previous
//
#include <hip/hip_runtime.h>
#include <hip/hip_bf16.h>
#include <stdint.h>

#define N_NODES 4096
#define INF_ 512
#define OUTF_ 512

typedef unsigned short u16;
typedef __attribute__((ext_vector_type(8))) short bf16x8;
typedef __attribute__((ext_vector_type(4))) float f32x4;

__device__ __forceinline__ u16 f2bf(float f) {
    union { float f; uint32_t u; } v; v.f = f;
    uint32_t u = v.u;
    uint32_t r = u + 0x7FFFu + ((u >> 16) & 1u);   // round-to-nearest-even
    return (u16)(r >> 16);
}

__device__ __forceinline__ void async16(const void* gsrc, void* ldst) {
    __builtin_amdgcn_global_load_lds(
        (const __attribute__((address_space(1))) unsigned int*)gsrc,
        (__attribute__((address_space(3))) unsigned int*)ldst,
        16, 0, 0);
}

// ---- fused prep: edge weights (dominant, BW-bound) + X/W bf16 converts ----
// grid 8192 x 256 = 2M threads; edges: 16M (8 per thread)
__global__ void prep_kernel(const float4* __restrict__ E4, const float* __restrict__ wq,
                            u16* __restrict__ Abf,
                            const float* __restrict__ X, const float* __restrict__ W,
                            u16* __restrict__ Xbf, u16* __restrict__ WT) {
    const int tid = blockIdx.x * blockDim.x + threadIdx.x;
    const float w0 = wq[0], w1 = wq[1], w2 = wq[2], w3 = wq[3];

    // converts (first blocks only; tiny vs edge work)
    if (tid < N_NODES * INF_) Xbf[tid] = f2bf(X[tid]);
    if (tid < INF_ * OUTF_) {
        int n = tid >> 9, k = tid & 511;
        WT[tid] = f2bf(W[k * OUTF_ + n]);   // WT[n][k] = W[k][n]
    }

    const int lane = threadIdx.x & 63;
    const long wave = (long)(tid >> 6);
    const long base = wave * 512;
#pragma unroll
    for (int j = 0; j < 8; ++j) {
        long idx = base + j * 64 + lane;
        float4 e = E4[idx];
        Abf[idx] = f2bf(e.x * w0 + e.y * w1 + e.z * w2 + e.w * w3);
    }
}

// ---- bf16 MFMA GEMM, 64x128 tile, BK=32, 4 waves (2x2, wave-tile 32x64) ----
// A: [M][K] row-major bf16; B: [N][K] row-major bf16 (B^T layout). lda=ldb=K.
// TRANS_OUT: outT[col*N_NODES+row] = bf16(acc)            (support^T)
// PARTIAL  : outF[z*M*OUTF_ + row*OUTF_ + col] = acc      (split-K partials)
// else     : outF[row*OUTF_+col] = acc + bias[col]
template<bool TRANS_OUT, bool PARTIAL>
__global__ __launch_bounds__(256)
void gemm64(const u16* __restrict__ A, const u16* __restrict__ B,
            float* __restrict__ outF, u16* __restrict__ outT,
            const float* __restrict__ bias, int K, int KC) {
    __shared__ u16 As[64][32];
    __shared__ u16 Bs[128][32];

    const int tid  = threadIdx.x;
    const int lane = tid & 63;
    const int w    = tid >> 6;        // wave 0..3
    const int wr   = w >> 1;          // wave row 0..1 (32 rows each)
    const int wc   = w & 1;           // wave col 0..1 (64 cols each)
    const int brow = blockIdx.x * 64;
    const int bcol = blockIdx.y * 128;
    const int kt0  = blockIdx.z * KC;

    f32x4 acc[2][4] = {};

    const int srA = w * 16 + (lane >> 2);   // A staging row for this lane
    const int srB = w * 32 + (lane >> 2);   // B staging row (first of two)
    const int sc  = (lane & 3) * 8;         // k-elem offset (16B per lane)

    for (int kt = kt0; kt < kt0 + KC; kt += 32) {
        __syncthreads();
        async16(&A[(long)(brow + srA) * K + kt + sc],      &As[w * 16][0]);
        async16(&B[(long)(bcol + srB) * K + kt + sc],      &Bs[w * 32][0]);
        async16(&B[(long)(bcol + srB + 16) * K + kt + sc], &Bs[w * 32 + 16][0]);
        __syncthreads();

        bf16x8 af[2], bfr[4];
#pragma unroll
        for (int m = 0; m < 2; ++m)
            af[m] = *(const bf16x8*)&As[wr * 32 + m * 16 + (lane & 15)][(lane >> 4) * 8];
#pragma unroll
        for (int n = 0; n < 4; ++n)
            bfr[n] = *(const bf16x8*)&Bs[wc * 64 + n * 16 + (lane & 15)][(lane >> 4) * 8];
#pragma unroll
        for (int m = 0; m < 2; ++m)
#pragma unroll
            for (int n = 0; n < 4; ++n)
                acc[m][n] = __builtin_amdgcn_mfma_f32_16x16x32_bf16(af[m], bfr[n], acc[m][n], 0, 0, 0);
    }

    // C/D layout: col=lane&15, row=(lane>>4)*4+reg  [verified m89/m91]
    float* outP = PARTIAL ? outF + (long)blockIdx.z * (N_NODES * OUTF_) : outF;
#pragma unroll
    for (int m = 0; m < 2; ++m) {
#pragma unroll
        for (int n = 0; n < 4; ++n) {
            int col  = bcol + wc * 64 + n * 16 + (lane & 15);
            int row0 = brow + wr * 32 + m * 16 + (lane >> 4) * 4;
            if (TRANS_OUT) {
#pragma unroll
                for (int r = 0; r < 4; ++r)
                    outT[(long)col * N_NODES + row0 + r] = f2bf(acc[m][n][r]);
            } else if (PARTIAL) {
#pragma unroll
                for (int r = 0; r < 4; ++r)
                    outP[(long)(row0 + r) * OUTF_ + col] = acc[m][n][r];
            } else {
                float bv = bias[col];
#pragma unroll
                for (int r = 0; r < 4; ++r)
                    outF[(long)(row0 + r) * OUTF_ + col] = acc[m][n][r] + bv;
            }
        }
    }
}

// ---- reduce split-K partials + bias: out = sum_z partial[z] + bias ----
__global__ void reduce_kernel(const float4* __restrict__ part, const float4* __restrict__ bias4,
                              float4* __restrict__ out) {
    const int tid = blockIdx.x * blockDim.x + threadIdx.x;   // 512K threads, 4 floats each
    const long stride4 = (long)N_NODES * OUTF_ / 4;
    float4 a = part[tid];
    float4 b = part[tid + stride4];
    float4 c = part[tid + 2 * stride4];
    float4 d = part[tid + 3 * stride4];
    float4 bv = bias4[tid & (OUTF_ / 4 - 1)];
    float4 o;
    o.x = a.x + b.x + c.x + d.x + bv.x;
    o.y = a.y + b.y + c.y + d.y + bv.y;
    o.z = a.z + b.z + c.z + d.z + bv.z;
    o.w = a.w + b.w + c.w + d.w + bv.w;
    out[tid] = o;
}

extern "C" void kernel_launch(void* const* d_in, const int* in_sizes, int n_in,
                              void* d_out, int out_size, void* d_ws, size_t ws_size,
                              hipStream_t stream) {
    const float* X    = (const float*)d_in[0];
    // d_in[1] = adj, unused by forward
    const float* E    = (const float*)d_in[2];
    const float* W    = (const float*)d_in[3];
    const float* wq   = (const float*)d_in[4];
    const float* bias = (const float*)d_in[5];
    float* out = (float*)d_out;

    char* ws = (char*)d_ws;
    // layout: ST [0,4M) ; Abf [4M,36M) ; Xbf [36M,40M) ; WT [40M,40.5M) ; partials [41M,73M)
    u16*   ST    = (u16*)ws;                        // 512 x 4096 bf16 (support^T)
    u16*   Abf   = (u16*)(ws + (4l << 20));         // 4096 x 4096 bf16
    u16*   Xbf   = (u16*)(ws + (36l << 20));        // 4096 x 512 bf16
    u16*   WT    = (u16*)(ws + (40l << 20));        // 512 x 512 bf16
    float* parts = (float*)(ws + (41l << 20));      // 4 x 4096 x 512 fp32

    const bool split = ws_size >= (73ul << 20);

    // 1) fused edge + converts (BW-bound, ~46us)
    prep_kernel<<<8192, 256, 0, stream>>>((const float4*)E, wq, Abf, X, W, Xbf, WT);
    // 2) support^T = (X @ W)^T in bf16 : grid 64x4 = 256 blocks
    gemm64<true, false><<<dim3(64, 4, 1), 256, 0, stream>>>(Xbf, WT, nullptr, ST, nullptr, 512, 512);
    // 3) out = Abf @ support + bias
    if (split) {
        gemm64<false, true><<<dim3(64, 4, 4), 256, 0, stream>>>(Abf, ST, parts, nullptr, nullptr, 4096, 1024);
        reduce_kernel<<<2048, 256, 0, stream>>>((const float4*)parts, (const float4*)bias, (float4*)out);
    } else {
        gemm64<false, false><<<dim3(64, 4, 1), 256, 0, stream>>>(Abf, ST, out, nullptr, bias, 4096, 4096);
    }
}